// Round 3
// baseline (604.397 us; speedup 1.0000x reference)
//
#include <hip/hip_runtime.h>
#include <hip/hip_bf16.h>
#include <stdint.h>

#define NATOMS 50000
#define NINT   800000
#define NFM    128
#define VOFF   (NATOMS*NFM)

typedef __bf16 bf16x8 __attribute__((ext_vector_type(8)));
typedef float  f32x4  __attribute__((ext_vector_type(4)));
typedef unsigned short u16;
typedef u16 u16x8 __attribute__((ext_vector_type(8)));

__device__ __forceinline__ u16 f2b(float f){
  uint32_t u = __float_as_uint(f);
  u += 0x7fffu + ((u >> 16) & 1u);   // RNE truncate to bf16
  return (u16)(u >> 16);
}
__device__ __forceinline__ float b2f(u16 b){ return __uint_as_float(((uint32_t)b) << 16); }

__device__ __forceinline__ float sspf(float x){
  // softplus(x) - ln2, stable, via native v_exp_f32/v_log_f32:
  // max(x,0) + ln2*log2(1 + 2^(-|x|*log2e)) - ln2
  float t = exp2f(-fabsf(x) * 1.44269504088896f);
  return fmaxf(x, 0.0f) + 0.69314718055995f * log2f(1.0f + t) - 0.69314718055995f;
}

// ---- weight prep: transpose 128x128 f32 -> bf16 Wt[n][k] = W[k][n] ----
__global__ void prep_weights_k(const float* __restrict__ w0, const float* __restrict__ w1,
                               const float* __restrict__ w2, const float* __restrict__ w3,
                               const float* __restrict__ w4, u16* __restrict__ wt){
  const float* srcs[5] = {w0, w1, w2, w3, w4};
  const float* src = srcs[blockIdx.x];
  u16* dst = wt + (size_t)blockIdx.x * NFM * NFM;
  for (int i = threadIdx.x; i < NFM*NFM; i += blockDim.x){
    int n = i >> 7, k = i & 127;
    dst[i] = f2b(src[k*NFM + n]);
  }
}

// ---- stage 256x128 f32 rows -> swizzled bf16 LDS tile (512 threads) ----
__device__ __forceinline__ void stage_inp(u16* lsA, const float* __restrict__ src,
                                          int base_row, int n_total, int t){
  #pragma unroll
  for (int pp = 0; pp < 8; ++pp){
    int id  = pp*512 + t;
    int row = id >> 4, c = id & 15;
    int grow = base_row + row;
    float4 v0 = make_float4(0.f,0.f,0.f,0.f), v1 = v0;
    if (grow < n_total){
      const float4* gp = reinterpret_cast<const float4*>(src + (size_t)grow*NFM + c*8);
      v0 = gp[0]; v1 = gp[1];
    }
    u16x8 pk;
    pk[0]=f2b(v0.x); pk[1]=f2b(v0.y); pk[2]=f2b(v0.z); pk[3]=f2b(v0.w);
    pk[4]=f2b(v1.x); pk[5]=f2b(v1.y); pk[6]=f2b(v1.z); pk[7]=f2b(v1.w);
    int byte = row*256 + ((c*16) ^ ((row & 7) << 4));
    *reinterpret_cast<u16x8*>(reinterpret_cast<char*>(lsA) + byte) = pk;
  }
}

// ---- stage 128x128 bf16 weight tile (already transposed in ws) -> swizzled LDS ----
__device__ __forceinline__ void stage_w(u16* lsW, const u16* __restrict__ wt, int t){
  #pragma unroll
  for (int pp = 0; pp < 4; ++pp){
    int id = pp*512 + t;
    int n = id >> 4, c = id & 15;
    u16x8 v = *reinterpret_cast<const u16x8*>(wt + n*NFM + c*8);
    int byte = n*256 + ((c*16) ^ ((n & 7) << 4));
    *reinterpret_cast<u16x8*>(reinterpret_cast<char*>(lsW) + byte) = v;
  }
}

// ---- per-wave 32x128 GEMM, A from swizzled LDS, B from LDS ----
__device__ __forceinline__ void gemm_tile(const u16* lsA, const u16* lsW,
                                          int wrow, int l15, int lk, f32x4 acc[2][8]){
  #pragma unroll
  for (int ks = 0; ks < 4; ++ks){
    int kb2 = (ks*32 + lk*8) * 2;
    int r0 = wrow + l15, r1 = wrow + 16 + l15;
    bf16x8 a0 = *reinterpret_cast<const bf16x8*>(reinterpret_cast<const char*>(lsA) + r0*256 + (kb2 ^ ((r0 & 7) << 4)));
    bf16x8 a1 = *reinterpret_cast<const bf16x8*>(reinterpret_cast<const char*>(lsA) + r1*256 + (kb2 ^ ((r1 & 7) << 4)));
    #pragma unroll
    for (int ni = 0; ni < 8; ++ni){
      int n = ni*16 + l15;
      bf16x8 b = *reinterpret_cast<const bf16x8*>(reinterpret_cast<const char*>(lsW) + n*256 + (kb2 ^ ((n & 7) << 4)));
      acc[0][ni] = __builtin_amdgcn_mfma_f32_16x16x32_bf16(a0, b, acc[0][ni], 0, 0, 0);
      acc[1][ni] = __builtin_amdgcn_mfma_f32_16x16x32_bf16(a1, b, acc[1][ni], 0, 0, 0);
    }
  }
}

// ---- per-wave 32x128 GEMM, A from swizzled LDS, B direct from global (L2-hot) ----
__device__ __forceinline__ void gemm_tile_g(const u16* lsA, const u16* __restrict__ wt,
                                            int wrow, int l15, int lk, f32x4 acc[2][8]){
  #pragma unroll
  for (int ks = 0; ks < 4; ++ks){
    int kb2 = (ks*32 + lk*8) * 2;
    int r0 = wrow + l15, r1 = wrow + 16 + l15;
    bf16x8 a0 = *reinterpret_cast<const bf16x8*>(reinterpret_cast<const char*>(lsA) + r0*256 + (kb2 ^ ((r0 & 7) << 4)));
    bf16x8 a1 = *reinterpret_cast<const bf16x8*>(reinterpret_cast<const char*>(lsA) + r1*256 + (kb2 ^ ((r1 & 7) << 4)));
    #pragma unroll
    for (int ni = 0; ni < 8; ++ni){
      int n = ni*16 + l15;
      bf16x8 b = *reinterpret_cast<const bf16x8*>(wt + n*NFM + ks*32 + lk*8);
      acc[0][ni] = __builtin_amdgcn_mfma_f32_16x16x32_bf16(a0, b, acc[0][ni], 0, 0, 0);
      acc[1][ni] = __builtin_amdgcn_mfma_f32_16x16x32_bf16(a1, b, acc[1][ni], 0, 0, 0);
    }
  }
}

// ---- f = x @ W_in2fac ----
__global__ __launch_bounds__(512, 2) void in2fac_k(const float* __restrict__ x,
                                                   const u16* __restrict__ wt,
                                                   float* __restrict__ f_g){
  __shared__ u16 lsA[256*128];
  __shared__ u16 lsW[128*128];
  int t = threadIdx.x;
  int B0 = blockIdx.x * 256;
  stage_inp(lsA, x, B0, NATOMS, t);
  stage_w(lsW, wt, t);
  __syncthreads();
  int wid = t >> 6, lane = t & 63, l15 = lane & 15, lk = lane >> 4;
  int wrow = wid * 32;
  f32x4 acc[2][8] = {};
  gemm_tile(lsA, lsW, wrow, l15, lk, acc);
  #pragma unroll
  for (int mi = 0; mi < 2; ++mi)
    #pragma unroll
    for (int ni = 0; ni < 8; ++ni)
      #pragma unroll
      for (int j = 0; j < 4; ++j){
        int grow = B0 + wrow + mi*16 + lk*4 + j;
        if (grow < NATOMS) f_g[(size_t)grow*NFM + ni*16 + l15] = acc[mi][ni][j];
      }
}

// ---- the big fused interaction kernel (v3: despilled — LDS caps us at 2 blocks/CU,
//      so ask for 2 waves/EU -> VGPR cap 256, accumulators stay in registers) ----
__global__ __launch_bounds__(512, 2) void cfnet_inter_k(
    const float* __restrict__ dijk, const int* __restrict__ idx_j, const int* __restrict__ seg_i,
    const float* __restrict__ b_f1, const float* __restrict__ b_f2,
    const u16* __restrict__ wt1, const u16* __restrict__ wt2,
    const float* __restrict__ f_g, float* __restrict__ conv){
  __shared__ u16 lsA[256*128];      // dijk tile -> h tile -> w tile (all bf16, swizzled)
  __shared__ int lsSeg[256];
  __shared__ int lsIdx[256];
  int t = threadIdx.x;
  int B0 = blockIdx.x * 256;
  if (t < 256){ lsSeg[t] = seg_i[B0 + t]; lsIdx[t] = idx_j[B0 + t]; }
  stage_inp(lsA, dijk, B0, NINT, t);
  __syncthreads();

  int wid = t >> 6, lane = t & 63, l15 = lane & 15, lk = lane >> 4;
  int wrow = wid * 32;
  float bias1[8], bias2[8];
  #pragma unroll
  for (int ni = 0; ni < 8; ++ni){ bias1[ni] = b_f1[ni*16 + l15]; bias2[ni] = b_f2[ni*16 + l15]; }

  // GEMM1: h = ssp(dijk @ W_f1 + b1) -> bf16 back into own rows of lsA
  {
    f32x4 acc1[2][8] = {};
    gemm_tile_g(lsA, wt1, wrow, l15, lk, acc1);
    #pragma unroll
    for (int mi = 0; mi < 2; ++mi)
      #pragma unroll
      for (int ni = 0; ni < 8; ++ni)
        #pragma unroll
        for (int j = 0; j < 4; ++j){
          int row = wrow + mi*16 + lk*4 + j;
          int col = ni*16 + l15;
          u16 hb = f2b(sspf(acc1[mi][ni][j] + bias1[ni]));
          int byte = row*256 + ((col*2) ^ ((row & 7) << 4));
          *reinterpret_cast<u16*>(reinterpret_cast<char*>(lsA) + byte) = hb;
        }
  }

  // GEMM2: w = ssp(h @ W_f2 + b2) -> bf16 back into own rows of lsA
  // (wave reads only its own 32 rows before overwriting them; LDS ops are
  //  in-order per wave, so no barrier needed between h-read and w-write)
  {
    f32x4 acc2[2][8] = {};
    gemm_tile_g(lsA, wt2, wrow, l15, lk, acc2);
    #pragma unroll
    for (int mi = 0; mi < 2; ++mi)
      #pragma unroll
      for (int ni = 0; ni < 8; ++ni)
        #pragma unroll
        for (int j = 0; j < 4; ++j){
          int row = wrow + mi*16 + lk*4 + j;
          int col = ni*16 + l15;
          u16 wb = f2b(sspf(acc2[mi][ni][j] + bias2[ni]));
          int byte = row*256 + ((col*2) ^ ((row & 7) << 4));
          *reinterpret_cast<u16*>(reinterpret_cast<char*>(lsA) + byte) = wb;
        }
  }
  __syncthreads();

  // fused gather * w + run-merged segment reduction
  // thread t -> col = t&127, quarter q = t>>7 (rows 64q .. 64q+63)
  {
    int col = t & 127, q = t >> 7;
    int qs = q << 6, qe = qs + 64;
    int prevseg = (qs > 0) ? lsSeg[qs-1] : (B0 > 0 ? seg_i[B0-1] : -1);
    int nextseg = (qe < 256) ? lsSeg[qe] : (B0 + 256 < NINT ? seg_i[B0+256] : -1);
    float wsum = 0.f;
    int cur = lsSeg[qs], rs = qs;
    #pragma unroll 8
    for (int r = qs; r < qe; ++r){
      int s = lsSeg[r];
      float fv = f_g[(size_t)lsIdx[r]*NFM + col];
      u16 wb = *reinterpret_cast<const u16*>(reinterpret_cast<const char*>(lsA)
                 + r*256 + ((col*2) ^ ((r & 7) << 4)));
      float wv = b2f(wb);
      if (s != cur){
        float* dp = conv + (size_t)cur*NFM + col;
        if (rs == qs && prevseg == cur) atomicAdd(dp, wsum); else *dp = wsum;
        cur = s; rs = r; wsum = 0.f;
      }
      wsum = fmaf(wv, fv, wsum);
    }
    float* dp = conv + (size_t)cur*NFM + col;
    if ((rs == qs && prevseg == cur) || nextseg == cur) atomicAdd(dp, wsum); else *dp = wsum;
  }
}

// ---- c = ssp(conv@W3+b3); v = c@W4+b4; y = x+v; out = [y ; v] ----
__global__ __launch_bounds__(512, 2) void out_k(const float* __restrict__ conv,
    const float* __restrict__ x, const u16* __restrict__ wt3, const u16* __restrict__ wt4,
    const float* __restrict__ b3, const float* __restrict__ b4, float* __restrict__ out){
  __shared__ u16 lsA[256*128];
  __shared__ u16 lsW1[128*128];
  __shared__ u16 lsW2[128*128];
  int t = threadIdx.x;
  int B0 = blockIdx.x * 256;
  stage_inp(lsA, conv, B0, NATOMS, t);
  stage_w(lsW1, wt3, t);
  stage_w(lsW2, wt4, t);
  __syncthreads();
  int wid = t >> 6, lane = t & 63, l15 = lane & 15, lk = lane >> 4;
  int wrow = wid * 32;
  float bias3[8], bias4[8];
  #pragma unroll
  for (int ni = 0; ni < 8; ++ni){ bias3[ni] = b3[ni*16 + l15]; bias4[ni] = b4[ni*16 + l15]; }

  f32x4 acc1[2][8] = {};
  gemm_tile(lsA, lsW1, wrow, l15, lk, acc1);
  #pragma unroll
  for (int mi = 0; mi < 2; ++mi)
    #pragma unroll
    for (int ni = 0; ni < 8; ++ni)
      #pragma unroll
      for (int j = 0; j < 4; ++j){
        int row = wrow + mi*16 + lk*4 + j;
        int col = ni*16 + l15;
        u16 hb = f2b(sspf(acc1[mi][ni][j] + bias3[ni]));
        int byte = row*256 + ((col*2) ^ ((row & 7) << 4));
        *reinterpret_cast<u16*>(reinterpret_cast<char*>(lsA) + byte) = hb;
      }

  f32x4 acc2[2][8] = {};
  gemm_tile(lsA, lsW2, wrow, l15, lk, acc2);
  #pragma unroll
  for (int mi = 0; mi < 2; ++mi)
    #pragma unroll
    for (int ni = 0; ni < 8; ++ni)
      #pragma unroll
      for (int j = 0; j < 4; ++j){
        int grow = B0 + wrow + mi*16 + lk*4 + j;
        if (grow < NATOMS){
          int col = ni*16 + l15;
          float v = acc2[mi][ni][j] + bias4[ni];
          float yv = x[(size_t)grow*NFM + col] + v;
          out[(size_t)grow*NFM + col] = yv;
          out[(size_t)VOFF + (size_t)grow*NFM + col] = v;
        }
      }
}

extern "C" void kernel_launch(void* const* d_in, const int* in_sizes, int n_in,
                              void* d_out, int out_size, void* d_ws, size_t ws_size,
                              hipStream_t stream){
  const float* x        = (const float*)d_in[0];
  const float* dijk     = (const float*)d_in[1];
  const int*   idx_j    = (const int*)d_in[2];
  const int*   seg_i    = (const int*)d_in[3];
  // d_in[4] = seg_j (identity, unused), d_in[5] = seg_i_sum (unused)
  const float* W_f1     = (const float*)d_in[6];
  const float* b_f1     = (const float*)d_in[7];
  const float* W_f2     = (const float*)d_in[8];
  const float* b_f2     = (const float*)d_in[9];
  const float* W_in2fac = (const float*)d_in[10];
  const float* W_fac2o  = (const float*)d_in[11];
  const float* b_fac2o  = (const float*)d_in[12];
  const float* W_dense  = (const float*)d_in[13];
  const float* b_dense  = (const float*)d_in[14];
  float* out = (float*)d_out;

  char* ws = (char*)d_ws;
  float* f_g  = (float*)ws;                       // 25.6 MB
  float* conv = (float*)(ws + 25600000);          // 25.6 MB
  u16*   wt   = (u16*)(ws + 51200000);            // 5 x 32 KB bf16 transposed weights
  u16* wt1 = wt;             // W_f1^T
  u16* wt2 = wt + 16384;     // W_f2^T
  u16* wt5 = wt + 2*16384;   // W_in2fac^T
  u16* wt3 = wt + 3*16384;   // W_fac2out^T
  u16* wt4 = wt + 4*16384;   // W_dense^T

  prep_weights_k<<<5, 256, 0, stream>>>(W_f1, W_f2, W_in2fac, W_fac2o, W_dense, wt);
  hipMemsetAsync(conv, 0, (size_t)NATOMS*NFM*sizeof(float), stream);
  in2fac_k<<<(NATOMS + 255)/256, 512, 0, stream>>>(x, wt5, f_g);
  cfnet_inter_k<<<NINT/256, 512, 0, stream>>>(dijk, idx_j, seg_i, b_f1, b_f2, wt1, wt2, f_g, conv);
  out_k<<<(NATOMS + 255)/256, 512, 0, stream>>>(conv, x, wt3, wt4, b_fac2o, b_dense, out);
}

// Round 4
// 468.308 us; speedup vs baseline: 1.2906x; 1.2906x over previous
//
#include <hip/hip_runtime.h>
#include <hip/hip_bf16.h>
#include <stdint.h>

#define NATOMS 50000
#define NINT   800000
#define NFM    128
#define VOFF   (NATOMS*NFM)

typedef __bf16 bf16x8 __attribute__((ext_vector_type(8)));
typedef float  f32x4  __attribute__((ext_vector_type(4)));
typedef unsigned short u16;
typedef u16 u16x8 __attribute__((ext_vector_type(8)));

__device__ __forceinline__ u16 f2b(float f){
  uint32_t u = __float_as_uint(f);
  u += 0x7fffu + ((u >> 16) & 1u);   // RNE truncate to bf16
  return (u16)(u >> 16);
}
__device__ __forceinline__ float b2f(u16 b){ return __uint_as_float(((uint32_t)b) << 16); }

__device__ __forceinline__ float sspf(float x){
  // softplus(x) - ln2, stable, native v_exp_f32/v_log_f32
  float t = exp2f(-fabsf(x) * 1.44269504088896f);
  return fmaxf(x, 0.0f) + 0.69314718055995f * log2f(1.0f + t) - 0.69314718055995f;
}

// ---- weight prep: transpose 128x128 f32 -> bf16 Wt[n][k] = W[k][n] ----
__global__ void prep_weights_k(const float* __restrict__ w0, const float* __restrict__ w1,
                               const float* __restrict__ w2, const float* __restrict__ w3,
                               const float* __restrict__ w4, u16* __restrict__ wt){
  const float* srcs[5] = {w0, w1, w2, w3, w4};
  const float* src = srcs[blockIdx.x];
  u16* dst = wt + (size_t)blockIdx.x * NFM * NFM;
  for (int i = threadIdx.x; i < NFM*NFM; i += blockDim.x){
    int n = i >> 7, k = i & 127;
    dst[i] = f2b(src[k*NFM + n]);
  }
}

// ---- stage 256x128 f32 rows -> swizzled bf16 LDS tile (512 threads) ----
__device__ __forceinline__ void stage_inp(u16* lsA, const float* __restrict__ src,
                                          int base_row, int n_total, int t){
  #pragma unroll
  for (int pp = 0; pp < 8; ++pp){
    int id  = pp*512 + t;
    int row = id >> 4, c = id & 15;
    int grow = base_row + row;
    float4 v0 = make_float4(0.f,0.f,0.f,0.f), v1 = v0;
    if (grow < n_total){
      const float4* gp = reinterpret_cast<const float4*>(src + (size_t)grow*NFM + c*8);
      v0 = gp[0]; v1 = gp[1];
    }
    u16x8 pk;
    pk[0]=f2b(v0.x); pk[1]=f2b(v0.y); pk[2]=f2b(v0.z); pk[3]=f2b(v0.w);
    pk[4]=f2b(v1.x); pk[5]=f2b(v1.y); pk[6]=f2b(v1.z); pk[7]=f2b(v1.w);
    int byte = row*256 + ((c*16) ^ ((row & 7) << 4));
    *reinterpret_cast<u16x8*>(reinterpret_cast<char*>(lsA) + byte) = pk;
  }
}

// ---- stage 128x128 bf16 weight tile -> swizzled LDS (512 threads) ----
__device__ __forceinline__ void stage_w(u16* lsW, const u16* __restrict__ wt, int t){
  #pragma unroll
  for (int pp = 0; pp < 4; ++pp){
    int id = pp*512 + t;
    int n = id >> 4, c = id & 15;
    u16x8 v = *reinterpret_cast<const u16x8*>(wt + n*NFM + c*8);
    int byte = n*256 + ((c*16) ^ ((n & 7) << 4));
    *reinterpret_cast<u16x8*>(reinterpret_cast<char*>(lsW) + byte) = v;
  }
}

// ---- per-wave 32x128 GEMM, A from swizzled LDS, B from LDS ----
__device__ __forceinline__ void gemm_tile(const u16* lsA, const u16* lsW,
                                          int wrow, int l15, int lk, f32x4 acc[2][8]){
  #pragma unroll
  for (int ks = 0; ks < 4; ++ks){
    int kb2 = (ks*32 + lk*8) * 2;
    int r0 = wrow + l15, r1 = wrow + 16 + l15;
    bf16x8 a0 = *reinterpret_cast<const bf16x8*>(reinterpret_cast<const char*>(lsA) + r0*256 + (kb2 ^ ((r0 & 7) << 4)));
    bf16x8 a1 = *reinterpret_cast<const bf16x8*>(reinterpret_cast<const char*>(lsA) + r1*256 + (kb2 ^ ((r1 & 7) << 4)));
    #pragma unroll
    for (int ni = 0; ni < 8; ++ni){
      int n = ni*16 + l15;
      bf16x8 b = *reinterpret_cast<const bf16x8*>(reinterpret_cast<const char*>(lsW) + n*256 + (kb2 ^ ((n & 7) << 4)));
      acc[0][ni] = __builtin_amdgcn_mfma_f32_16x16x32_bf16(a0, b, acc[0][ni], 0, 0, 0);
      acc[1][ni] = __builtin_amdgcn_mfma_f32_16x16x32_bf16(a1, b, acc[1][ni], 0, 0, 0);
    }
  }
}

// ---- f = x @ W_in2fac ----
__global__ __launch_bounds__(512, 2) void in2fac_k(const float* __restrict__ x,
                                                   const u16* __restrict__ wt,
                                                   float* __restrict__ f_g){
  __shared__ u16 lsA[256*128];
  __shared__ u16 lsW[128*128];
  int t = threadIdx.x;
  int B0 = blockIdx.x * 256;
  stage_inp(lsA, x, B0, NATOMS, t);
  stage_w(lsW, wt, t);
  __syncthreads();
  int wid = t >> 6, lane = t & 63, l15 = lane & 15, lk = lane >> 4;
  int wrow = wid * 32;
  f32x4 acc[2][8] = {};
  gemm_tile(lsA, lsW, wrow, l15, lk, acc);
  #pragma unroll
  for (int mi = 0; mi < 2; ++mi)
    #pragma unroll
    for (int ni = 0; ni < 8; ++ni)
      #pragma unroll
      for (int j = 0; j < 4; ++j){
        int grow = B0 + wrow + mi*16 + lk*4 + j;
        if (grow < NATOMS) f_g[(size_t)grow*NFM + ni*16 + l15] = acc[mi][ni][j];
      }
}

// ---- fused interaction kernel v4: A in regs, shared 32KB W slot, 2 blocks/CU ----
__global__ __launch_bounds__(512) __attribute__((amdgpu_waves_per_eu(4, 4)))
void cfnet_inter_k(
    const float* __restrict__ dijk, const int* __restrict__ idx_j, const int* __restrict__ seg_i,
    const float* __restrict__ b_f1, const float* __restrict__ b_f2,
    const u16* __restrict__ wt1, const u16* __restrict__ wt2,
    const float* __restrict__ f_g, float* __restrict__ conv){
  __shared__ u16 lsW[128*128];    // 32 KB: W1, then W2
  __shared__ u16 lsBuf[256*64];   // 32 KB: per-wave h scratch, then w staging halves
  __shared__ int lsSeg[256];
  __shared__ int lsIdx[256];
  int t = threadIdx.x;
  int B0 = blockIdx.x * 256;   // NINT % 256 == 0, no row guards needed
  int wid = t >> 6, lane = t & 63, l15 = lane & 15, lk = lane >> 4;

  // A-fragment loads global -> regs (MFMA layout), issued first to hide HBM latency
  float4 af[16];
  const float* abase = dijk + (size_t)(B0 + wid*32 + l15) * NFM;
  #pragma unroll
  for (int mi = 0; mi < 2; ++mi)
    #pragma unroll
    for (int ks = 0; ks < 4; ++ks){
      const float4* gp = reinterpret_cast<const float4*>(abase + mi*16*NFM + ks*32 + lk*8);
      af[(mi*4+ks)*2+0] = gp[0];
      af[(mi*4+ks)*2+1] = gp[1];
    }

  if (t < 256){ lsSeg[t] = seg_i[B0 + t]; lsIdx[t] = idx_j[B0 + t]; }
  stage_w(lsW, wt1, t);

  float bias1[8], bias2[8];
  #pragma unroll
  for (int ni = 0; ni < 8; ++ni){ bias1[ni] = b_f1[ni*16 + l15]; bias2[ni] = b_f2[ni*16 + l15]; }

  // pack A f32 -> bf16 fragments
  bf16x8 a[2][4];
  #pragma unroll
  for (int mi = 0; mi < 2; ++mi)
    #pragma unroll
    for (int ks = 0; ks < 4; ++ks){
      float4 v0 = af[(mi*4+ks)*2], v1 = af[(mi*4+ks)*2+1];
      u16x8 pk;
      pk[0]=f2b(v0.x); pk[1]=f2b(v0.y); pk[2]=f2b(v0.z); pk[3]=f2b(v0.w);
      pk[4]=f2b(v1.x); pk[5]=f2b(v1.y); pk[6]=f2b(v1.z); pk[7]=f2b(v1.w);
      a[mi][ks] = *reinterpret_cast<bf16x8*>(&pk);
    }

  __syncthreads();   // W1 + seg/idx ready

  // GEMM1: acc = A @ W1 (B from LDS)
  f32x4 acc[2][8] = {};
  #pragma unroll
  for (int ks = 0; ks < 4; ++ks){
    int kb2 = (ks*32 + lk*8) * 2;
    #pragma unroll
    for (int ni = 0; ni < 8; ++ni){
      int n = ni*16 + l15;
      bf16x8 b = *reinterpret_cast<const bf16x8*>(reinterpret_cast<const char*>(lsW) + n*256 + (kb2 ^ ((n & 7) << 4)));
      acc[0][ni] = __builtin_amdgcn_mfma_f32_16x16x32_bf16(a[0][ks], b, acc[0][ni], 0, 0, 0);
      acc[1][ni] = __builtin_amdgcn_mfma_f32_16x16x32_bf16(a[1][ks], b, acc[1][ni], 0, 0, 0);
    }
  }

  // h = ssp(acc + b1): redistribute acc-layout -> A-fragment layout through
  // per-wave 4KB scratch (wave-private, in-order LDS, no barrier), 2 col-halves
  {
    char* wbase = reinterpret_cast<char*>(lsBuf) + wid*4096;
    #pragma unroll
    for (int p2 = 0; p2 < 2; ++p2){
      #pragma unroll
      for (int mi = 0; mi < 2; ++mi)
        #pragma unroll
        for (int nn = 0; nn < 4; ++nn){
          int ni = p2*4 + nn;
          int ch = nn*16 + l15;
          #pragma unroll
          for (int j = 0; j < 4; ++j){
            int r = mi*16 + lk*4 + j;
            u16 hb = f2b(sspf(acc[mi][ni][j] + bias1[ni]));
            *reinterpret_cast<u16*>(wbase + r*128 + ((ch*2) ^ ((r & 7) << 4))) = hb;
          }
        }
      #pragma unroll
      for (int mi = 0; mi < 2; ++mi)
        #pragma unroll
        for (int ksl = 0; ksl < 2; ++ksl){
          int rl = mi*16 + l15;
          a[mi][p2*2+ksl] = *reinterpret_cast<const bf16x8*>(wbase + rl*128 + ((ksl*64 + lk*16) ^ ((rl & 7) << 4)));
        }
    }
  }

  __syncthreads();          // all waves done with W1
  stage_w(lsW, wt2, t);     // swap in W2
  __syncthreads();

  // GEMM2: acc = h @ W2, then w = ssp(acc + b2) kept in regs (f32)
  #pragma unroll
  for (int mi = 0; mi < 2; ++mi)
    #pragma unroll
    for (int ni = 0; ni < 8; ++ni)
      acc[mi][ni] = (f32x4){0.f, 0.f, 0.f, 0.f};
  #pragma unroll
  for (int ks = 0; ks < 4; ++ks){
    int kb2 = (ks*32 + lk*8) * 2;
    #pragma unroll
    for (int ni = 0; ni < 8; ++ni){
      int n = ni*16 + l15;
      bf16x8 b = *reinterpret_cast<const bf16x8*>(reinterpret_cast<const char*>(lsW) + n*256 + (kb2 ^ ((n & 7) << 4)));
      acc[0][ni] = __builtin_amdgcn_mfma_f32_16x16x32_bf16(a[0][ks], b, acc[0][ni], 0, 0, 0);
      acc[1][ni] = __builtin_amdgcn_mfma_f32_16x16x32_bf16(a[1][ks], b, acc[1][ni], 0, 0, 0);
    }
  }
  #pragma unroll
  for (int mi = 0; mi < 2; ++mi)
    #pragma unroll
    for (int ni = 0; ni < 8; ++ni)
      #pragma unroll
      for (int j = 0; j < 4; ++j)
        acc[mi][ni][j] = sspf(acc[mi][ni][j] + bias2[ni]);

  // gather * w + run-merged segment reduce, 2 column-half passes,
  // 8 quarters x 32 rows each (thread t: quarter q=t>>6, col c=t&63)
  int cR = t & 63, q = t >> 6;
  int qs = q*32, qe = qs + 32;
  #pragma unroll
  for (int p = 0; p < 2; ++p){
    #pragma unroll
    for (int mi = 0; mi < 2; ++mi)
      #pragma unroll
      for (int nn = 0; nn < 4; ++nn){
        int ni = p*4 + nn;
        int ch = nn*16 + l15;
        #pragma unroll
        for (int j = 0; j < 4; ++j){
          int r = wid*32 + mi*16 + lk*4 + j;
          *reinterpret_cast<u16*>(reinterpret_cast<char*>(lsBuf) + r*128 + ((ch*2) ^ ((r & 7) << 4))) = f2b(acc[mi][ni][j]);
        }
      }
    __syncthreads();
    {
      int gcol = p*64 + cR;
      int prevseg = (qs > 0) ? lsSeg[qs-1] : (B0 > 0 ? seg_i[B0-1] : -1);
      int nextseg = (qe < 256) ? lsSeg[qe] : (B0 + 256 < NINT ? seg_i[B0+256] : -1);
      float wsum = 0.f;
      int cur = lsSeg[qs], rs = qs;
      #pragma unroll 8
      for (int r = qs; r < qe; ++r){
        int s = lsSeg[r];
        float fv = f_g[(size_t)lsIdx[r]*NFM + gcol];
        float wv = b2f(*reinterpret_cast<const u16*>(reinterpret_cast<const char*>(lsBuf) + r*128 + ((cR*2) ^ ((r & 7) << 4))));
        if (s != cur){
          float* dp = conv + (size_t)cur*NFM + gcol;
          if (rs == qs && prevseg == cur) atomicAdd(dp, wsum); else *dp = wsum;
          cur = s; rs = r; wsum = 0.f;
        }
        wsum = fmaf(wv, fv, wsum);
      }
      float* dp = conv + (size_t)cur*NFM + gcol;
      if ((rs == qs && prevseg == cur) || nextseg == cur) atomicAdd(dp, wsum); else *dp = wsum;
    }
    __syncthreads();
  }
}

// ---- c = ssp(conv@W3+b3); v = c@W4+b4; y = x+v; out = [y ; v] ----
__global__ __launch_bounds__(512, 2) void out_k(const float* __restrict__ conv,
    const float* __restrict__ x, const u16* __restrict__ wt3, const u16* __restrict__ wt4,
    const float* __restrict__ b3, const float* __restrict__ b4, float* __restrict__ out){
  __shared__ u16 lsA[256*128];
  __shared__ u16 lsW1[128*128];
  __shared__ u16 lsW2[128*128];
  int t = threadIdx.x;
  int B0 = blockIdx.x * 256;
  stage_inp(lsA, conv, B0, NATOMS, t);
  stage_w(lsW1, wt3, t);
  stage_w(lsW2, wt4, t);
  __syncthreads();
  int wid = t >> 6, lane = t & 63, l15 = lane & 15, lk = lane >> 4;
  int wrow = wid * 32;
  float bias3[8], bias4[8];
  #pragma unroll
  for (int ni = 0; ni < 8; ++ni){ bias3[ni] = b3[ni*16 + l15]; bias4[ni] = b4[ni*16 + l15]; }

  f32x4 acc1[2][8] = {};
  gemm_tile(lsA, lsW1, wrow, l15, lk, acc1);
  #pragma unroll
  for (int mi = 0; mi < 2; ++mi)
    #pragma unroll
    for (int ni = 0; ni < 8; ++ni)
      #pragma unroll
      for (int j = 0; j < 4; ++j){
        int row = wrow + mi*16 + lk*4 + j;
        int col = ni*16 + l15;
        u16 hb = f2b(sspf(acc1[mi][ni][j] + bias3[ni]));
        int byte = row*256 + ((col*2) ^ ((row & 7) << 4));
        *reinterpret_cast<u16*>(reinterpret_cast<char*>(lsA) + byte) = hb;
      }

  f32x4 acc2[2][8] = {};
  gemm_tile(lsA, lsW2, wrow, l15, lk, acc2);
  #pragma unroll
  for (int mi = 0; mi < 2; ++mi)
    #pragma unroll
    for (int ni = 0; ni < 8; ++ni)
      #pragma unroll
      for (int j = 0; j < 4; ++j){
        int grow = B0 + wrow + mi*16 + lk*4 + j;
        if (grow < NATOMS){
          int col = ni*16 + l15;
          float v = acc2[mi][ni][j] + bias4[ni];
          float yv = x[(size_t)grow*NFM + col] + v;
          out[(size_t)grow*NFM + col] = yv;
          out[(size_t)VOFF + (size_t)grow*NFM + col] = v;
        }
      }
}

extern "C" void kernel_launch(void* const* d_in, const int* in_sizes, int n_in,
                              void* d_out, int out_size, void* d_ws, size_t ws_size,
                              hipStream_t stream){
  const float* x        = (const float*)d_in[0];
  const float* dijk     = (const float*)d_in[1];
  const int*   idx_j    = (const int*)d_in[2];
  const int*   seg_i    = (const int*)d_in[3];
  // d_in[4] = seg_j (identity, unused), d_in[5] = seg_i_sum (unused)
  const float* W_f1     = (const float*)d_in[6];
  const float* b_f1     = (const float*)d_in[7];
  const float* W_f2     = (const float*)d_in[8];
  const float* b_f2     = (const float*)d_in[9];
  const float* W_in2fac = (const float*)d_in[10];
  const float* W_fac2o  = (const float*)d_in[11];
  const float* b_fac2o  = (const float*)d_in[12];
  const float* W_dense  = (const float*)d_in[13];
  const float* b_dense  = (const float*)d_in[14];
  float* out = (float*)d_out;

  char* ws = (char*)d_ws;
  float* f_g  = (float*)ws;                       // 25.6 MB
  float* conv = (float*)(ws + 25600000);          // 25.6 MB
  u16*   wt   = (u16*)(ws + 51200000);            // 5 x 32 KB bf16 transposed weights
  u16* wt1 = wt;             // W_f1^T
  u16* wt2 = wt + 16384;     // W_f2^T
  u16* wt5 = wt + 2*16384;   // W_in2fac^T
  u16* wt3 = wt + 3*16384;   // W_fac2out^T
  u16* wt4 = wt + 4*16384;   // W_dense^T

  prep_weights_k<<<5, 256, 0, stream>>>(W_f1, W_f2, W_in2fac, W_fac2o, W_dense, wt);
  hipMemsetAsync(conv, 0, (size_t)NATOMS*NFM*sizeof(float), stream);
  in2fac_k<<<(NATOMS + 255)/256, 512, 0, stream>>>(x, wt5, f_g);
  cfnet_inter_k<<<NINT/256, 512, 0, stream>>>(dijk, idx_j, seg_i, b_f1, b_f2, wt1, wt2, f_g, conv);
  out_k<<<(NATOMS + 255)/256, 512, 0, stream>>>(conv, x, wt3, wt4, b_fac2o, b_dense, out);
}

// Round 5
// 444.813 us; speedup vs baseline: 1.3588x; 1.0528x over previous
//
#include <hip/hip_runtime.h>
#include <hip/hip_bf16.h>
#include <stdint.h>

#define NATOMS 50000
#define NINT   800000
#define NFM    128
#define VOFF   (NATOMS*NFM)

typedef __bf16 bf16x8 __attribute__((ext_vector_type(8)));
typedef float  f32x4  __attribute__((ext_vector_type(4)));
typedef unsigned short u16;
typedef u16 u16x8 __attribute__((ext_vector_type(8)));

__device__ __forceinline__ u16 f2b(float f){
  uint32_t u = __float_as_uint(f);
  u += 0x7fffu + ((u >> 16) & 1u);   // RNE truncate to bf16
  return (u16)(u >> 16);
}
__device__ __forceinline__ float b2f(u16 b){ return __uint_as_float(((uint32_t)b) << 16); }

__device__ __forceinline__ float sspf(float x){
  // softplus(x) - ln2, stable, native v_exp_f32/v_log_f32
  float t = exp2f(-fabsf(x) * 1.44269504088896f);
  return fmaxf(x, 0.0f) + 0.69314718055995f * log2f(1.0f + t) - 0.69314718055995f;
}

// ---- weight prep: transpose 128x128 f32 -> bf16 Wt[n][k] = W[k][n] ----
__global__ void prep_weights_k(const float* __restrict__ w0, const float* __restrict__ w1,
                               const float* __restrict__ w2, const float* __restrict__ w3,
                               const float* __restrict__ w4, u16* __restrict__ wt){
  const float* srcs[5] = {w0, w1, w2, w3, w4};
  const float* src = srcs[blockIdx.x];
  u16* dst = wt + (size_t)blockIdx.x * NFM * NFM;
  for (int i = threadIdx.x; i < NFM*NFM; i += blockDim.x){
    int n = i >> 7, k = i & 127;
    dst[i] = f2b(src[k*NFM + n]);
  }
}

// ---- stage 256x128 f32 rows -> swizzled bf16 LDS tile (512 threads) ----
__device__ __forceinline__ void stage_inp(u16* lsA, const float* __restrict__ src,
                                          int base_row, int n_total, int t){
  #pragma unroll
  for (int pp = 0; pp < 8; ++pp){
    int id  = pp*512 + t;
    int row = id >> 4, c = id & 15;
    int grow = base_row + row;
    float4 v0 = make_float4(0.f,0.f,0.f,0.f), v1 = v0;
    if (grow < n_total){
      const float4* gp = reinterpret_cast<const float4*>(src + (size_t)grow*NFM + c*8);
      v0 = gp[0]; v1 = gp[1];
    }
    u16x8 pk;
    pk[0]=f2b(v0.x); pk[1]=f2b(v0.y); pk[2]=f2b(v0.z); pk[3]=f2b(v0.w);
    pk[4]=f2b(v1.x); pk[5]=f2b(v1.y); pk[6]=f2b(v1.z); pk[7]=f2b(v1.w);
    int byte = row*256 + ((c*16) ^ ((row & 7) << 4));
    *reinterpret_cast<u16x8*>(reinterpret_cast<char*>(lsA) + byte) = pk;
  }
}

// ---- stage 128x128 bf16 weight tile -> swizzled LDS (512 threads) ----
__device__ __forceinline__ void stage_w(u16* lsW, const u16* __restrict__ wt, int t){
  #pragma unroll
  for (int pp = 0; pp < 4; ++pp){
    int id = pp*512 + t;
    int n = id >> 4, c = id & 15;
    u16x8 v = *reinterpret_cast<const u16x8*>(wt + n*NFM + c*8);
    int byte = n*256 + ((c*16) ^ ((n & 7) << 4));
    *reinterpret_cast<u16x8*>(reinterpret_cast<char*>(lsW) + byte) = v;
  }
}

// ---- per-wave 32x128 GEMM, A from swizzled LDS, B from LDS ----
__device__ __forceinline__ void gemm_tile(const u16* lsA, const u16* lsW,
                                          int wrow, int l15, int lk, f32x4 acc[2][8]){
  #pragma unroll
  for (int ks = 0; ks < 4; ++ks){
    int kb2 = (ks*32 + lk*8) * 2;
    int r0 = wrow + l15, r1 = wrow + 16 + l15;
    bf16x8 a0 = *reinterpret_cast<const bf16x8*>(reinterpret_cast<const char*>(lsA) + r0*256 + (kb2 ^ ((r0 & 7) << 4)));
    bf16x8 a1 = *reinterpret_cast<const bf16x8*>(reinterpret_cast<const char*>(lsA) + r1*256 + (kb2 ^ ((r1 & 7) << 4)));
    #pragma unroll
    for (int ni = 0; ni < 8; ++ni){
      int n = ni*16 + l15;
      bf16x8 b = *reinterpret_cast<const bf16x8*>(reinterpret_cast<const char*>(lsW) + n*256 + (kb2 ^ ((n & 7) << 4)));
      acc[0][ni] = __builtin_amdgcn_mfma_f32_16x16x32_bf16(a0, b, acc[0][ni], 0, 0, 0);
      acc[1][ni] = __builtin_amdgcn_mfma_f32_16x16x32_bf16(a1, b, acc[1][ni], 0, 0, 0);
    }
  }
}

// ---- f = x @ W_in2fac, output bf16 ----
__global__ __launch_bounds__(512, 2) void in2fac_k(const float* __restrict__ x,
                                                   const u16* __restrict__ wt,
                                                   u16* __restrict__ f_g){
  __shared__ u16 lsA[256*128];
  __shared__ u16 lsW[128*128];
  int t = threadIdx.x;
  int B0 = blockIdx.x * 256;
  stage_inp(lsA, x, B0, NATOMS, t);
  stage_w(lsW, wt, t);
  __syncthreads();
  int wid = t >> 6, lane = t & 63, l15 = lane & 15, lk = lane >> 4;
  int wrow = wid * 32;
  f32x4 acc[2][8] = {};
  gemm_tile(lsA, lsW, wrow, l15, lk, acc);
  #pragma unroll
  for (int mi = 0; mi < 2; ++mi)
    #pragma unroll
    for (int ni = 0; ni < 8; ++ni)
      #pragma unroll
      for (int j = 0; j < 4; ++j){
        int grow = B0 + wrow + mi*16 + lk*4 + j;
        if (grow < NATOMS) f_g[(size_t)grow*NFM + ni*16 + l15] = f2b(acc[mi][ni][j]);
      }
}

// ---- fused interaction kernel v5: split-N (acc=32 regs), no bulk prefetch,
//      bf16 f_g gather; target: no spills at 4 waves/EU ----
__global__ __launch_bounds__(512) __attribute__((amdgpu_waves_per_eu(4, 4)))
void cfnet_inter_k(
    const float* __restrict__ dijk, const int* __restrict__ idx_j, const int* __restrict__ seg_i,
    const float* __restrict__ b_f1, const float* __restrict__ b_f2,
    const u16* __restrict__ wt1, const u16* __restrict__ wt2,
    const u16* __restrict__ f_g, float* __restrict__ conv){
  __shared__ u16 lsW[128*128];    // 32 KB: W1, then W2
  __shared__ u16 lsBuf[256*64];   // 32 KB: per-wave h scratch, then w staging halves
  __shared__ int lsSeg[256];
  __shared__ int lsIdx[256];
  int t = threadIdx.x;
  int B0 = blockIdx.x * 256;   // NINT % 256 == 0
  int wid = t >> 6, lane = t & 63, l15 = lane & 15, lk = lane >> 4;

  if (t < 256){ lsSeg[t] = seg_i[B0 + t]; lsIdx[t] = idx_j[B0 + t]; }
  stage_w(lsW, wt1, t);

  // A fragments: load f32, convert immediately (low live-range)
  bf16x8 a[2][4];
  const float* abase = dijk + (size_t)(B0 + wid*32 + l15) * NFM;
  #pragma unroll
  for (int mi = 0; mi < 2; ++mi)
    #pragma unroll
    for (int ks = 0; ks < 4; ++ks){
      const float4* gp = reinterpret_cast<const float4*>(abase + mi*16*NFM + ks*32 + lk*8);
      float4 v0 = gp[0], v1 = gp[1];
      u16x8 pk;
      pk[0]=f2b(v0.x); pk[1]=f2b(v0.y); pk[2]=f2b(v0.z); pk[3]=f2b(v0.w);
      pk[4]=f2b(v1.x); pk[5]=f2b(v1.y); pk[6]=f2b(v1.z); pk[7]=f2b(v1.w);
      a[mi][ks] = *reinterpret_cast<bf16x8*>(&pk);
    }

  float bias1[8], bias2[8];
  #pragma unroll
  for (int ni = 0; ni < 8; ++ni){ bias1[ni] = b_f1[ni*16 + l15]; bias2[ni] = b_f2[ni*16 + l15]; }

  __syncthreads();   // W1 + seg/idx ready

  // GEMM1 in two 64-col passes; h redistributed via per-wave 4KB scratch
  char* wbase = reinterpret_cast<char*>(lsBuf) + wid*4096;   // [32 rows][128 B]
  bf16x8 h[2][4];
  #pragma unroll
  for (int p = 0; p < 2; ++p){
    f32x4 acc[2][4] = {};
    #pragma unroll
    for (int ks = 0; ks < 4; ++ks){
      int kb2 = (ks*32 + lk*8) * 2;
      #pragma unroll
      for (int nn = 0; nn < 4; ++nn){
        int n = (p*4 + nn)*16 + l15;
        bf16x8 b = *reinterpret_cast<const bf16x8*>(reinterpret_cast<const char*>(lsW) + n*256 + (kb2 ^ ((n & 7) << 4)));
        acc[0][nn] = __builtin_amdgcn_mfma_f32_16x16x32_bf16(a[0][ks], b, acc[0][nn], 0, 0, 0);
        acc[1][nn] = __builtin_amdgcn_mfma_f32_16x16x32_bf16(a[1][ks], b, acc[1][nn], 0, 0, 0);
      }
    }
    // ssp -> bf16 -> wave-private scratch (cols of half p), then reload as k-fragments
    #pragma unroll
    for (int mi = 0; mi < 2; ++mi)
      #pragma unroll
      for (int nn = 0; nn < 4; ++nn){
        int ch = nn*16 + l15;
        #pragma unroll
        for (int j = 0; j < 4; ++j){
          int r = mi*16 + lk*4 + j;
          *reinterpret_cast<u16*>(wbase + r*128 + ((ch*2) ^ ((r & 7) << 4))) = f2b(sspf(acc[mi][nn][j] + bias1[p*4+nn]));
        }
      }
    #pragma unroll
    for (int mi = 0; mi < 2; ++mi)
      #pragma unroll
      for (int ksl = 0; ksl < 2; ++ksl){
        int rl = mi*16 + l15;
        h[mi][p*2+ksl] = *reinterpret_cast<const bf16x8*>(wbase + rl*128 + ((ksl*64 + lk*16) ^ ((rl & 7) << 4)));
      }
  }

  __syncthreads();          // h scratch reads done everywhere
  stage_w(lsW, wt2, t);     // swap in W2
  __syncthreads();

  // GEMM2 in two 64-col passes; each pass: ssp -> stage w half -> fused reduce
  int cR = t & 63, q = t >> 6;
  int qs = q*32, qe = qs + 32;
  #pragma unroll
  for (int p = 0; p < 2; ++p){
    f32x4 acc[2][4] = {};
    #pragma unroll
    for (int ks = 0; ks < 4; ++ks){
      int kb2 = (ks*32 + lk*8) * 2;
      #pragma unroll
      for (int nn = 0; nn < 4; ++nn){
        int n = (p*4 + nn)*16 + l15;
        bf16x8 b = *reinterpret_cast<const bf16x8*>(reinterpret_cast<const char*>(lsW) + n*256 + (kb2 ^ ((n & 7) << 4)));
        acc[0][nn] = __builtin_amdgcn_mfma_f32_16x16x32_bf16(h[0][ks], b, acc[0][nn], 0, 0, 0);
        acc[1][nn] = __builtin_amdgcn_mfma_f32_16x16x32_bf16(h[1][ks], b, acc[1][nn], 0, 0, 0);
      }
    }
    #pragma unroll
    for (int mi = 0; mi < 2; ++mi)
      #pragma unroll
      for (int nn = 0; nn < 4; ++nn){
        int ch = nn*16 + l15;
        #pragma unroll
        for (int j = 0; j < 4; ++j){
          int r = wid*32 + mi*16 + lk*4 + j;
          *reinterpret_cast<u16*>(reinterpret_cast<char*>(lsBuf) + r*128 + ((ch*2) ^ ((r & 7) << 4))) = f2b(sspf(acc[mi][nn][j] + bias2[p*4+nn]));
        }
      }
    __syncthreads();
    {
      int gcol = p*64 + cR;
      int prevseg = (qs > 0) ? lsSeg[qs-1] : (B0 > 0 ? seg_i[B0-1] : -1);
      int nextseg = (qe < 256) ? lsSeg[qe] : (B0 + 256 < NINT ? seg_i[B0+256] : -1);
      float wsum = 0.f;
      int cur = lsSeg[qs], rs = qs;
      #pragma unroll 8
      for (int r = qs; r < qe; ++r){
        int s = lsSeg[r];
        float fv = b2f(f_g[(size_t)lsIdx[r]*NFM + gcol]);
        float wv = b2f(*reinterpret_cast<const u16*>(reinterpret_cast<const char*>(lsBuf) + r*128 + ((cR*2) ^ ((r & 7) << 4))));
        if (s != cur){
          float* dp = conv + (size_t)cur*NFM + gcol;
          if (rs == qs && prevseg == cur) atomicAdd(dp, wsum); else *dp = wsum;
          cur = s; rs = r; wsum = 0.f;
        }
        wsum = fmaf(wv, fv, wsum);
      }
      float* dp = conv + (size_t)cur*NFM + gcol;
      if ((rs == qs && prevseg == cur) || nextseg == cur) atomicAdd(dp, wsum); else *dp = wsum;
    }
    __syncthreads();
  }
}

// ---- c = ssp(conv@W3+b3); v = c@W4+b4; y = x+v; out = [y ; v] ----
__global__ __launch_bounds__(512, 2) void out_k(const float* __restrict__ conv,
    const float* __restrict__ x, const u16* __restrict__ wt3, const u16* __restrict__ wt4,
    const float* __restrict__ b3, const float* __restrict__ b4, float* __restrict__ out){
  __shared__ u16 lsA[256*128];
  __shared__ u16 lsW1[128*128];
  __shared__ u16 lsW2[128*128];
  int t = threadIdx.x;
  int B0 = blockIdx.x * 256;
  stage_inp(lsA, conv, B0, NATOMS, t);
  stage_w(lsW1, wt3, t);
  stage_w(lsW2, wt4, t);
  __syncthreads();
  int wid = t >> 6, lane = t & 63, l15 = lane & 15, lk = lane >> 4;
  int wrow = wid * 32;
  float bias3[8], bias4[8];
  #pragma unroll
  for (int ni = 0; ni < 8; ++ni){ bias3[ni] = b3[ni*16 + l15]; bias4[ni] = b4[ni*16 + l15]; }

  f32x4 acc1[2][8] = {};
  gemm_tile(lsA, lsW1, wrow, l15, lk, acc1);
  #pragma unroll
  for (int mi = 0; mi < 2; ++mi)
    #pragma unroll
    for (int ni = 0; ni < 8; ++ni)
      #pragma unroll
      for (int j = 0; j < 4; ++j){
        int row = wrow + mi*16 + lk*4 + j;
        int col = ni*16 + l15;
        u16 hb = f2b(sspf(acc1[mi][ni][j] + bias3[ni]));
        int byte = row*256 + ((col*2) ^ ((row & 7) << 4));
        *reinterpret_cast<u16*>(reinterpret_cast<char*>(lsA) + byte) = hb;
      }

  f32x4 acc2[2][8] = {};
  gemm_tile(lsA, lsW2, wrow, l15, lk, acc2);
  #pragma unroll
  for (int mi = 0; mi < 2; ++mi)
    #pragma unroll
    for (int ni = 0; ni < 8; ++ni)
      #pragma unroll
      for (int j = 0; j < 4; ++j){
        int grow = B0 + wrow + mi*16 + lk*4 + j;
        if (grow < NATOMS){
          int col = ni*16 + l15;
          float v = acc2[mi][ni][j] + bias4[ni];
          float yv = x[(size_t)grow*NFM + col] + v;
          out[(size_t)grow*NFM + col] = yv;
          out[(size_t)VOFF + (size_t)grow*NFM + col] = v;
        }
      }
}

extern "C" void kernel_launch(void* const* d_in, const int* in_sizes, int n_in,
                              void* d_out, int out_size, void* d_ws, size_t ws_size,
                              hipStream_t stream){
  const float* x        = (const float*)d_in[0];
  const float* dijk     = (const float*)d_in[1];
  const int*   idx_j    = (const int*)d_in[2];
  const int*   seg_i    = (const int*)d_in[3];
  // d_in[4] = seg_j (identity, unused), d_in[5] = seg_i_sum (unused)
  const float* W_f1     = (const float*)d_in[6];
  const float* b_f1     = (const float*)d_in[7];
  const float* W_f2     = (const float*)d_in[8];
  const float* b_f2     = (const float*)d_in[9];
  const float* W_in2fac = (const float*)d_in[10];
  const float* W_fac2o  = (const float*)d_in[11];
  const float* b_fac2o  = (const float*)d_in[12];
  const float* W_dense  = (const float*)d_in[13];
  const float* b_dense  = (const float*)d_in[14];
  float* out = (float*)d_out;

  char* ws = (char*)d_ws;
  u16*   f_g  = (u16*)ws;                         // 12.8 MB (bf16)
  float* conv = (float*)(ws + 12800000);          // 25.6 MB
  u16*   wt   = (u16*)(ws + 38400000);            // 5 x 32 KB bf16 transposed weights
  u16* wt1 = wt;             // W_f1^T
  u16* wt2 = wt + 16384;     // W_f2^T
  u16* wt5 = wt + 2*16384;   // W_in2fac^T
  u16* wt3 = wt + 3*16384;   // W_fac2out^T
  u16* wt4 = wt + 4*16384;   // W_dense^T

  prep_weights_k<<<5, 256, 0, stream>>>(W_f1, W_f2, W_in2fac, W_fac2o, W_dense, wt);
  hipMemsetAsync(conv, 0, (size_t)NATOMS*NFM*sizeof(float), stream);
  in2fac_k<<<(NATOMS + 255)/256, 512, 0, stream>>>(x, wt5, f_g);
  cfnet_inter_k<<<NINT/256, 512, 0, stream>>>(dijk, idx_j, seg_i, b_f1, b_f2, wt1, wt2, f_g, conv);
  out_k<<<(NATOMS + 255)/256, 512, 0, stream>>>(conv, x, wt3, wt4, b_fac2o, b_dense, out);
}

// Round 8
// 367.869 us; speedup vs baseline: 1.6430x; 1.2092x over previous
//
#include <hip/hip_runtime.h>
#include <hip/hip_bf16.h>
#include <stdint.h>

#define NATOMS 50000
#define NINT   800000
#define NFM    128
#define VOFF   (NATOMS*NFM)

typedef __bf16 bf16x8 __attribute__((ext_vector_type(8)));
typedef float  f32x4  __attribute__((ext_vector_type(4)));
typedef unsigned short u16;
typedef u16 u16x8 __attribute__((ext_vector_type(8)));

__device__ __forceinline__ u16 f2b(float f){
  uint32_t u = __float_as_uint(f);
  u += 0x7fffu + ((u >> 16) & 1u);   // RNE truncate to bf16
  return (u16)(u >> 16);
}
__device__ __forceinline__ float b2f(u16 b){ return __uint_as_float(((uint32_t)b) << 16); }

__device__ __forceinline__ float sspf(float x){
  // softplus(x) - ln2, stable, native v_exp_f32/v_log_f32
  float t = exp2f(-fabsf(x) * 1.44269504088896f);
  return fmaxf(x, 0.0f) + 0.69314718055995f * log2f(1.0f + t) - 0.69314718055995f;
}

// ---- weight prep: transpose 128x128 f32 -> bf16 Wt[n][k] = W[k][n] ----
__global__ void prep_weights_k(const float* __restrict__ w0, const float* __restrict__ w1,
                               const float* __restrict__ w2, const float* __restrict__ w3,
                               const float* __restrict__ w4, u16* __restrict__ wt){
  const float* srcs[5] = {w0, w1, w2, w3, w4};
  const float* src = srcs[blockIdx.x];
  u16* dst = wt + (size_t)blockIdx.x * NFM * NFM;
  for (int i = threadIdx.x; i < NFM*NFM; i += blockDim.x){
    int n = i >> 7, k = i & 127;
    dst[i] = f2b(src[k*NFM + n]);
  }
}

// ---- stage 256x128 f32 rows -> swizzled bf16 LDS tile (512 threads) ----
__device__ __forceinline__ void stage_inp(u16* lsA, const float* __restrict__ src,
                                          int base_row, int n_total, int t){
  #pragma unroll
  for (int pp = 0; pp < 8; ++pp){
    int id  = pp*512 + t;
    int row = id >> 4, c = id & 15;
    int grow = base_row + row;
    float4 v0 = make_float4(0.f,0.f,0.f,0.f), v1 = v0;
    if (grow < n_total){
      const float4* gp = reinterpret_cast<const float4*>(src + (size_t)grow*NFM + c*8);
      v0 = gp[0]; v1 = gp[1];
    }
    u16x8 pk;
    pk[0]=f2b(v0.x); pk[1]=f2b(v0.y); pk[2]=f2b(v0.z); pk[3]=f2b(v0.w);
    pk[4]=f2b(v1.x); pk[5]=f2b(v1.y); pk[6]=f2b(v1.z); pk[7]=f2b(v1.w);
    int byte = row*256 + ((c*16) ^ ((row & 7) << 4));
    *reinterpret_cast<u16x8*>(reinterpret_cast<char*>(lsA) + byte) = pk;
  }
}

// ---- stage 128x128 bf16 weight tile -> swizzled LDS (512 threads) ----
__device__ __forceinline__ void stage_w(u16* lsW, const u16* __restrict__ wt, int t){
  #pragma unroll
  for (int pp = 0; pp < 4; ++pp){
    int id = pp*512 + t;
    int n = id >> 4, c = id & 15;
    u16x8 v = *reinterpret_cast<const u16x8*>(wt + n*NFM + c*8);
    int byte = n*256 + ((c*16) ^ ((n & 7) << 4));
    *reinterpret_cast<u16x8*>(reinterpret_cast<char*>(lsW) + byte) = v;
  }
}

// ---- per-wave 32x128 GEMM, A from swizzled LDS, B from LDS ----
__device__ __forceinline__ void gemm_tile(const u16* lsA, const u16* lsW,
                                          int wrow, int l15, int lk, f32x4 acc[2][8]){
  #pragma unroll
  for (int ks = 0; ks < 4; ++ks){
    int kb2 = (ks*32 + lk*8) * 2;
    int r0 = wrow + l15, r1 = wrow + 16 + l15;
    bf16x8 a0 = *reinterpret_cast<const bf16x8*>(reinterpret_cast<const char*>(lsA) + r0*256 + (kb2 ^ ((r0 & 7) << 4)));
    bf16x8 a1 = *reinterpret_cast<const bf16x8*>(reinterpret_cast<const char*>(lsA) + r1*256 + (kb2 ^ ((r1 & 7) << 4)));
    #pragma unroll
    for (int ni = 0; ni < 8; ++ni){
      int n = ni*16 + l15;
      bf16x8 b = *reinterpret_cast<const bf16x8*>(reinterpret_cast<const char*>(lsW) + n*256 + (kb2 ^ ((n & 7) << 4)));
      acc[0][ni] = __builtin_amdgcn_mfma_f32_16x16x32_bf16(a0, b, acc[0][ni], 0, 0, 0);
      acc[1][ni] = __builtin_amdgcn_mfma_f32_16x16x32_bf16(a1, b, acc[1][ni], 0, 0, 0);
    }
  }
}

// ---- f = x @ W_in2fac, output bf16 ----
__global__ __launch_bounds__(512, 2) void in2fac_k(const float* __restrict__ x,
                                                   const u16* __restrict__ wt,
                                                   u16* __restrict__ f_g){
  __shared__ u16 lsA[256*128];
  __shared__ u16 lsW[128*128];
  int t = threadIdx.x;
  int B0 = blockIdx.x * 256;
  stage_inp(lsA, x, B0, NATOMS, t);
  stage_w(lsW, wt, t);
  __syncthreads();
  int wid = t >> 6, lane = t & 63, l15 = lane & 15, lk = lane >> 4;
  int wrow = wid * 32;
  f32x4 acc[2][8] = {};
  gemm_tile(lsA, lsW, wrow, l15, lk, acc);
  #pragma unroll
  for (int mi = 0; mi < 2; ++mi)
    #pragma unroll
    for (int ni = 0; ni < 8; ++ni)
      #pragma unroll
      for (int j = 0; j < 4; ++j){
        int grow = B0 + wrow + mi*16 + lk*4 + j;
        if (grow < NATOMS) f_g[(size_t)grow*NFM + ni*16 + l15] = f2b(acc[mi][ni][j]);
      }
}

// ---- fused interaction kernel v6: mi-split GEMM1 (A and h never co-resident),
//      target live set < 128 regs at 4 waves/EU ----
__global__ __launch_bounds__(512) __attribute__((amdgpu_waves_per_eu(4, 4)))
void cfnet_inter_k(
    const float* __restrict__ dijk, const int* __restrict__ idx_j, const int* __restrict__ seg_i,
    const float* __restrict__ b_f1, const float* __restrict__ b_f2,
    const u16* __restrict__ wt1, const u16* __restrict__ wt2,
    const u16* __restrict__ f_g, float* __restrict__ conv){
  __shared__ u16 lsW[128*128];    // 32 KB: W1, then W2
  __shared__ u16 lsBuf[256*64];   // 32 KB: per-wave h scratch (16x128), then w staging halves
  __shared__ int lsSeg[256];
  __shared__ int lsIdx[256];
  int t = threadIdx.x;
  int B0 = blockIdx.x * 256;   // NINT % 256 == 0
  int wid = t >> 6, lane = t & 63, l15 = lane & 15, lk = lane >> 4;

  if (t < 256){ lsSeg[t] = seg_i[B0 + t]; lsIdx[t] = idx_j[B0 + t]; }
  stage_w(lsW, wt1, t);

  float bias1[8];
  #pragma unroll
  for (int ni = 0; ni < 8; ++ni) bias1[ni] = b_f1[ni*16 + l15];

  __syncthreads();   // W1 + seg/idx ready

  // GEMM1, mi-split: per 16-row half, load A frags (die at half end),
  // full-width acc[8], ssp -> wave-private scratch (16x128 bf16), reload h frags
  char* wbase = reinterpret_cast<char*>(lsBuf) + wid*4096;   // 16 rows x 256 B
  bf16x8 h[2][4];
  #pragma unroll
  for (int mi = 0; mi < 2; ++mi){
    bf16x8 a[4];
    const float* abase = dijk + (size_t)(B0 + wid*32 + mi*16 + l15) * NFM;
    #pragma unroll
    for (int ks = 0; ks < 4; ++ks){
      const float4* gp = reinterpret_cast<const float4*>(abase + ks*32 + lk*8);
      float4 v0 = gp[0], v1 = gp[1];
      u16x8 pk;
      pk[0]=f2b(v0.x); pk[1]=f2b(v0.y); pk[2]=f2b(v0.z); pk[3]=f2b(v0.w);
      pk[4]=f2b(v1.x); pk[5]=f2b(v1.y); pk[6]=f2b(v1.z); pk[7]=f2b(v1.w);
      a[ks] = *reinterpret_cast<bf16x8*>(&pk);
    }
    f32x4 acc[8] = {};
    #pragma unroll
    for (int ks = 0; ks < 4; ++ks){
      int kb2 = (ks*32 + lk*8) * 2;
      #pragma unroll
      for (int ni = 0; ni < 8; ++ni){
        int n = ni*16 + l15;
        bf16x8 b = *reinterpret_cast<const bf16x8*>(reinterpret_cast<const char*>(lsW) + n*256 + (kb2 ^ ((n & 7) << 4)));
        acc[ni] = __builtin_amdgcn_mfma_f32_16x16x32_bf16(a[ks], b, acc[ni], 0, 0, 0);
      }
    }
    // ssp -> bf16 -> scratch (local rows r = lk*4+j, cols ni*16+l15)
    #pragma unroll
    for (int ni = 0; ni < 8; ++ni){
      int col = ni*16 + l15;
      #pragma unroll
      for (int j = 0; j < 4; ++j){
        int r = lk*4 + j;
        *reinterpret_cast<u16*>(wbase + r*256 + ((col*2) ^ ((r & 7) << 4))) = f2b(sspf(acc[ni][j] + bias1[ni]));
      }
    }
    // reload as A-layout k-fragments: row l15, k-slice ks
    #pragma unroll
    for (int ks = 0; ks < 4; ++ks){
      h[mi][ks] = *reinterpret_cast<const bf16x8*>(wbase + l15*256 + (((ks*32 + lk*8)*2) ^ ((l15 & 7) << 4)));
    }
  }

  float bias2[8];
  #pragma unroll
  for (int ni = 0; ni < 8; ++ni) bias2[ni] = b_f2[ni*16 + l15];

  __syncthreads();          // h scratch reads done everywhere
  stage_w(lsW, wt2, t);     // swap in W2
  __syncthreads();

  // GEMM2 in two 64-col passes; each pass: ssp -> stage w half -> fused reduce
  int cR = t & 63, q = t >> 6;
  int qs = q*32, qe = qs + 32;
  #pragma unroll
  for (int p = 0; p < 2; ++p){
    f32x4 acc[2][4] = {};
    #pragma unroll
    for (int ks = 0; ks < 4; ++ks){
      int kb2 = (ks*32 + lk*8) * 2;
      #pragma unroll
      for (int nn = 0; nn < 4; ++nn){
        int n = (p*4 + nn)*16 + l15;
        bf16x8 b = *reinterpret_cast<const bf16x8*>(reinterpret_cast<const char*>(lsW) + n*256 + (kb2 ^ ((n & 7) << 4)));
        acc[0][nn] = __builtin_amdgcn_mfma_f32_16x16x32_bf16(h[0][ks], b, acc[0][nn], 0, 0, 0);
        acc[1][nn] = __builtin_amdgcn_mfma_f32_16x16x32_bf16(h[1][ks], b, acc[1][nn], 0, 0, 0);
      }
    }
    #pragma unroll
    for (int mi = 0; mi < 2; ++mi)
      #pragma unroll
      for (int nn = 0; nn < 4; ++nn){
        int ch = nn*16 + l15;
        #pragma unroll
        for (int j = 0; j < 4; ++j){
          int r = wid*32 + mi*16 + lk*4 + j;
          *reinterpret_cast<u16*>(reinterpret_cast<char*>(lsBuf) + r*128 + ((ch*2) ^ ((r & 7) << 4))) = f2b(sspf(acc[mi][nn][j] + bias2[p*4+nn]));
        }
      }
    __syncthreads();
    {
      int gcol = p*64 + cR;
      int prevseg = (qs > 0) ? lsSeg[qs-1] : (B0 > 0 ? seg_i[B0-1] : -1);
      int nextseg = (qe < 256) ? lsSeg[qe] : (B0 + 256 < NINT ? seg_i[B0+256] : -1);
      float wsum = 0.f;
      int cur = lsSeg[qs], rs = qs;
      #pragma unroll 8
      for (int r = qs; r < qe; ++r){
        int s = lsSeg[r];
        float fv = b2f(f_g[(size_t)lsIdx[r]*NFM + gcol]);
        float wv = b2f(*reinterpret_cast<const u16*>(reinterpret_cast<const char*>(lsBuf) + r*128 + ((cR*2) ^ ((r & 7) << 4))));
        if (s != cur){
          float* dp = conv + (size_t)cur*NFM + gcol;
          if (rs == qs && prevseg == cur) atomicAdd(dp, wsum); else *dp = wsum;
          cur = s; rs = r; wsum = 0.f;
        }
        wsum = fmaf(wv, fv, wsum);
      }
      float* dp = conv + (size_t)cur*NFM + gcol;
      if ((rs == qs && prevseg == cur) || nextseg == cur) atomicAdd(dp, wsum); else *dp = wsum;
    }
    __syncthreads();
  }
}

// ---- c = ssp(conv@W3+b3); v = c@W4+b4; y = x+v; out = [y ; v] ----
__global__ __launch_bounds__(512, 2) void out_k(const float* __restrict__ conv,
    const float* __restrict__ x, const u16* __restrict__ wt3, const u16* __restrict__ wt4,
    const float* __restrict__ b3, const float* __restrict__ b4, float* __restrict__ out){
  __shared__ u16 lsA[256*128];
  __shared__ u16 lsW1[128*128];
  __shared__ u16 lsW2[128*128];
  int t = threadIdx.x;
  int B0 = blockIdx.x * 256;
  stage_inp(lsA, conv, B0, NATOMS, t);
  stage_w(lsW1, wt3, t);
  stage_w(lsW2, wt4, t);
  __syncthreads();
  int wid = t >> 6, lane = t & 63, l15 = lane & 15, lk = lane >> 4;
  int wrow = wid * 32;
  float bias3[8], bias4[8];
  #pragma unroll
  for (int ni = 0; ni < 8; ++ni){ bias3[ni] = b3[ni*16 + l15]; bias4[ni] = b4[ni*16 + l15]; }

  f32x4 acc1[2][8] = {};
  gemm_tile(lsA, lsW1, wrow, l15, lk, acc1);
  #pragma unroll
  for (int mi = 0; mi < 2; ++mi)
    #pragma unroll
    for (int ni = 0; ni < 8; ++ni)
      #pragma unroll
      for (int j = 0; j < 4; ++j){
        int row = wrow + mi*16 + lk*4 + j;
        int col = ni*16 + l15;
        u16 hb = f2b(sspf(acc1[mi][ni][j] + bias3[ni]));
        int byte = row*256 + ((col*2) ^ ((row & 7) << 4));
        *reinterpret_cast<u16*>(reinterpret_cast<char*>(lsA) + byte) = hb;
      }

  f32x4 acc2[2][8] = {};
  gemm_tile(lsA, lsW2, wrow, l15, lk, acc2);
  #pragma unroll
  for (int mi = 0; mi < 2; ++mi)
    #pragma unroll
    for (int ni = 0; ni < 8; ++ni)
      #pragma unroll
      for (int j = 0; j < 4; ++j){
        int grow = B0 + wrow + mi*16 + lk*4 + j;
        if (grow < NATOMS){
          int col = ni*16 + l15;
          float v = acc2[mi][ni][j] + bias4[ni];
          float yv = x[(size_t)grow*NFM + col] + v;
          out[(size_t)grow*NFM + col] = yv;
          out[(size_t)VOFF + (size_t)grow*NFM + col] = v;
        }
      }
}

extern "C" void kernel_launch(void* const* d_in, const int* in_sizes, int n_in,
                              void* d_out, int out_size, void* d_ws, size_t ws_size,
                              hipStream_t stream){
  const float* x        = (const float*)d_in[0];
  const float* dijk     = (const float*)d_in[1];
  const int*   idx_j    = (const int*)d_in[2];
  const int*   seg_i    = (const int*)d_in[3];
  // d_in[4] = seg_j (identity, unused), d_in[5] = seg_i_sum (unused)
  const float* W_f1     = (const float*)d_in[6];
  const float* b_f1     = (const float*)d_in[7];
  const float* W_f2     = (const float*)d_in[8];
  const float* b_f2     = (const float*)d_in[9];
  const float* W_in2fac = (const float*)d_in[10];
  const float* W_fac2o  = (const float*)d_in[11];
  const float* b_fac2o  = (const float*)d_in[12];
  const float* W_dense  = (const float*)d_in[13];
  const float* b_dense  = (const float*)d_in[14];
  float* out = (float*)d_out;

  char* ws = (char*)d_ws;
  u16*   f_g  = (u16*)ws;                         // 12.8 MB (bf16)
  float* conv = (float*)(ws + 12800000);          // 25.6 MB
  u16*   wt   = (u16*)(ws + 38400000);            // 5 x 32 KB bf16 transposed weights
  u16* wt1 = wt;             // W_f1^T
  u16* wt2 = wt + 16384;     // W_f2^T
  u16* wt5 = wt + 2*16384;   // W_in2fac^T
  u16* wt3 = wt + 3*16384;   // W_fac2out^T
  u16* wt4 = wt + 4*16384;   // W_dense^T

  prep_weights_k<<<5, 256, 0, stream>>>(W_f1, W_f2, W_in2fac, W_fac2o, W_dense, wt);
  hipMemsetAsync(conv, 0, (size_t)NATOMS*NFM*sizeof(float), stream);
  in2fac_k<<<(NATOMS + 255)/256, 512, 0, stream>>>(x, wt5, f_g);
  cfnet_inter_k<<<NINT/256, 512, 0, stream>>>(dijk, idx_j, seg_i, b_f1, b_f2, wt1, wt2, f_g, conv);
  out_k<<<(NATOMS + 255)/256, 512, 0, stream>>>(conv, x, wt3, wt4, b_fac2o, b_dense, out);
}